// Round 9
// baseline (4177.306 us; speedup 1.0000x reference)
//
#include <hip/hip_runtime.h>
#include <math.h>

// DCRNN encoder: one block per batch element (64 blocks x 1024 thr = 16 waves).
// Round-9: round-8 structure + (a) explicit amdgpu_num_vgpr(128) register
// request (allocator was budgeting 64 and spilling ~2-3 GB of scratch traffic),
// (b) gates dense phases split into U-pass -> ua -> fence -> R-pass so the
// dual 32-reg accumulator never exists (peak live ~95 < 128).
// 8-phase schedule, two diffusion buffers XCA/XCB, no accumulator lives across
// a diffusion; x0 dense fragments via scalar reads from transposed buffers.
// S2=2*S@S precomputed; x2=S2@x0-x0 with -x0 folded into W (W0' = W0-W2).
// Layer-0 x-part precomputed for all T (xpack), added in epilogue.

typedef unsigned short u16;
typedef unsigned int u32;
typedef short bf8 __attribute__((ext_vector_type(8)));
typedef u16 u16x4 __attribute__((ext_vector_type(4)));
typedef u16 u16x8 __attribute__((ext_vector_type(8)));
typedef float f32x4 __attribute__((ext_vector_type(4)));

constexpr int T_ = 24, B_ = 64, N_ = 207, H_ = 64;
constexpr int BNH = B_ * N_ * H_;      // 847872

// LDS map (total exactly 163840 B = 160 KiB)
constexpr int XT0 = 0;                 // 28672: [64 h][224 m] bf16 h0^T, pitch 448, ^((h&7)<<4)
constexpr int XTR = 28672;             // 28672: transposed scratch (rh0 / h1 / rh1)
constexpr int XCA = 57344;             // 53248: [208 n][128 k] bf16 diff out A, pitch 256, ^((n&7)<<4)
constexpr int XCB = 110592;            // 53248: diff out B
constexpr int LDS_TOTAL = 163840;

#define MFMA(a, bb, c) __builtin_amdgcn_mfma_f32_16x16x32_bf16(a, bb, c, 0, 0, 0)

__device__ __forceinline__ float b2f(u16 b) {
    u32 u = ((u32)b) << 16; float f; __builtin_memcpy(&f, &u, 4); return f;
}
__device__ __forceinline__ u16 f2b(float f) {
    u32 u; __builtin_memcpy(&u, &f, 4);
    return (u16)((u + 0x7FFF + ((u >> 16) & 1)) >> 16);
}
__device__ __forceinline__ float sigm(float v) { return 1.f / (1.f + __expf(-v)); }
__device__ __forceinline__ float tanh_f(float v) {
    return 1.f - 2.f / (__expf(2.f * v) + 1.f);
}

// ---------------------------------------------------------------- S2 = 2*S@S
__global__ void s2_kernel(const float* __restrict__ S, float* __restrict__ S2) {
    const int n = blockIdx.x, m = threadIdx.x;
    if (m >= N_) return;
    float acc = 0.f;
    for (int k = 0; k < N_; ++k) acc += S[n * N_ + k] * S[k * N_ + m];
    S2[n * N_ + m] = 2.f * acc;
}

// ---------------------- S fragments: sfr[half 2][rt 13][ks 7][lane 64][j 8]
__global__ void sfr_build(const float* __restrict__ S, const float* __restrict__ S2,
                          u16* __restrict__ sfr) {
    int idx = blockIdx.x * 256 + threadIdx.x;
    if (idx >= 2 * 13 * 7 * 64 * 8) return;   // 93184
    int jj = idx & 7;
    int lane = (idx >> 3) & 63;
    int rest = idx >> 9;
    int ks = rest % 7; rest /= 7;
    int rt = rest % 13, half = rest / 13;
    int node = rt * 16 + (lane & 15);
    int k = ks * 32 + (lane >> 4) * 8 + jj;
    float v = 0.f;
    if (node < N_ && k < N_) v = half ? S2[node * N_ + k] : S[node * N_ + k];
    sfr[idx] = f2b(v);
}

// ------------------------------------------------ W blocked to fragment order
__global__ void wblk_build(const float* __restrict__ W, u16* __restrict__ out,
                           int OF, int total, int layer) {
    int idx = blockIdx.x * 256 + threadIdx.x;
    if (idx >= total) return;
    int j = idx & 7;
    int rest = idx >> 3;
    int o = rest % OF; rest /= OF;
    int kb = rest & 3, ks = rest >> 2;
    int k = ks * 32 + kb * 8 + j;
    int blk = k >> 6, d = k & 63;
    int wrow, wsub = -1;
    if (layer == 0) {                       // [x0h, x1h, x2h], D=66
        wrow = blk * 66 + 2 + d;
        if (blk == 0) wsub = 2 * 66 + 2 + d;
    } else {                                // [x0x,x0h,x1x,x1h,x2x,x2h], D=128
        int sb = blk >> 1, part = blk & 1;
        wrow = sb * 128 + part * 64 + d;
        if (sb == 0) wsub = 256 + part * 64 + d;
    }
    float v = W[wrow * OF + o];
    if (wsub >= 0) v -= W[wsub * OF + o];
    out[idx] = f2b(v);
}

// ------------------------------------- layer-0 x-feature weight slice (f32)
__global__ void wx_build(const float* __restrict__ W, float* __restrict__ out, int OF) {
    int idx = blockIdx.x * 256 + threadIdx.x;
    if (idx >= 6 * OF) return;
    int o = idx % OF, p = idx / OF;
    int cheb = p >> 1, i = p & 1;
    float v = W[(cheb * 66 + i) * OF + o];
    if (cheb == 0) v -= W[(132 + i) * OF + o];
    out[idx] = v;
}

// ------------------------------------- x transpose: [T,B,N,2] -> [n][t][b][i]
__global__ void xt2_build(const float* __restrict__ x, u16* __restrict__ xt2) {
    int idx = blockIdx.x * 256 + threadIdx.x;
    if (idx >= N_ * T_ * B_ * 2) return;
    int i = idx & 1, b = (idx >> 1) & 63, rest = idx >> 7;
    int t = rest % T_, n = rest / T_;
    xt2[idx] = f2b(x[((t * B_ + b) * N_ + n) * 2 + i]);
}

// ----------------- layer-0 x part, all T: xpack[b][t][n][8] = [x0,x1,S@x,S2@x]
__global__ __launch_bounds__(256) void xpack_build(const float* __restrict__ S,
                                                   const float* __restrict__ S2,
                                                   const u16* __restrict__ xt2,
                                                   float* __restrict__ xpack) {
    __shared__ float sS[N_], sS2[N_];
    int n = blockIdx.x;
    for (int i = threadIdx.x; i < N_; i += 256) { sS[i] = S[n*N_+i]; sS2[i] = S2[n*N_+i]; }
    __syncthreads();
    int c = blockIdx.y * 256 + threadIdx.x;   // < 1536 = T*B
    float a10 = 0, a11 = 0, a20 = 0, a21 = 0;
    for (int m = 0; m < N_; ++m) {
        float x0 = b2f(xt2[m * 3072 + c * 2]);
        float x1 = b2f(xt2[m * 3072 + c * 2 + 1]);
        a10 += sS[m] * x0;  a11 += sS[m] * x1;
        a20 += sS2[m] * x0; a21 += sS2[m] * x1;
    }
    int t = c >> 6, bb = c & 63;
    float* p = xpack + (size_t)((bb * 24 + t) * N_ + n) * 8;
    p[0] = b2f(xt2[n * 3072 + c * 2]); p[1] = b2f(xt2[n * 3072 + c * 2 + 1]);
    p[2] = a10; p[3] = a11; p[4] = a20; p[5] = a21; p[6] = 0.f; p[7] = 0.f;
}

// --------------------------------------------------------------- scan kernel
__global__ __launch_bounds__(1024)
__attribute__((amdgpu_num_vgpr(128), amdgpu_waves_per_eu(4, 4)))
void dcrnn_scan(
    const u16* __restrict__ sfr,
    const u16* __restrict__ wg0b, const float* __restrict__ bg0, const float* __restrict__ wxg0,
    const u16* __restrict__ wc0b, const float* __restrict__ bc0, const float* __restrict__ wxc0,
    const u16* __restrict__ wg1b, const float* __restrict__ bg1,
    const u16* __restrict__ wc1b, const float* __restrict__ bc1,
    const float* __restrict__ xpack, const float* __restrict__ ih,
    float* __restrict__ out_hid, float* __restrict__ out_cur)
{
    extern __shared__ char lds[];
    const int tid  = threadIdx.x;
    const int lane = tid & 63, wid = tid >> 6;        // 16 waves
    const int lq = lane >> 4, lr = lane & 15;
    const int j = wid >> 2, rg = wid & 3;             // o-tile j, node-split rg
    const int o = j * 16 + lr;
    const int b = blockIdx.x;

    // ---- zero all LDS (pads must be finite-zero)
    {
        u16x8 z = {0,0,0,0,0,0,0,0};
        for (int i = tid; i < LDS_TOTAL / 16; i += 1024)
            *(u16x8*)(lds + i * 16) = z;
    }
    __syncthreads();

    // ---- init: XT0 <- h0^T ; masters from ih (clamped-group duplicates)
    const float* ih0 = ih + (size_t)b * 13248;
    const float* ih1 = ih + (size_t)BNH + (size_t)b * 13248;
    for (int idx = tid; idx < 13248; idx += 1024) {
        int n = idx >> 6, oo = idx & 63;
        *(u16*)(lds + XT0 + ((oo * 448 + n * 2) ^ ((oo & 7) << 4))) = f2b(ih0[idx]);
    }
    float h0m[4][4], h1m[4][4], ua[4][4];
#pragma unroll
    for (int i = 0; i < 4; ++i) {
        int g = rg + 4 * i; if (g > 12) g = 12;
#pragma unroll
        for (int jj = 0; jj < 4; ++jj) {
            int n = g * 16 + lq * 4 + jj;
            h0m[i][jj] = (n < 207) ? ih0[n * 64 + o] : 0.f;
            h1m[i][jj] = (n < 207) ? ih1[n * 64 + o] : 0.f;
            ua[i][jj] = 0.f;
        }
    }
    __syncthreads();

    // ---- helpers
    auto ldXC = [&](int base, int g, int koff) -> bf8 {
        int row = g * 16 + lr;
        return *(const bf8*)(lds + base + ((row * 256 + koff * 2) ^ ((row & 7) << 4)));
    };
    // x0 A-fragment from a transposed buffer: 8 scalar reads (f = ks*32+8lq+j)
    auto ldX0T = [&](int xtOff, int g, int ks) -> bf8 {
        bf8 r;
        const int n2 = (g * 16 + lr) * 2;
        const int fb = ks * 32 + lq * 8;
#pragma unroll
        for (int e = 0; e < 8; ++e)
            r[e] = *(const short*)(lds + xtOff + (((fb + e) * 448 + n2) ^ ((e & 7) << 4)));
        return r;
    };
    auto xtW = [&](int dst, int g, u16x4 hv) {
        int nb = g * 16 + lq * 4;
        *(u16x4*)(lds + dst + ((o * 448 + nb * 2) ^ ((o & 7) << 4))) = hv;
    };
    auto ldW = [&](const u16* w, int OF, int ks, int oo) -> bf8 {
        return *(const bf8*)(w + (size_t)((ks * 4 + lq) * OF + oo) * 8);
    };
    // diffusion tasks: (rt,ct) grid; dual-phase runs 104 tasks (two src/dst pairs)
    auto diffuseTasks = [&](int src0, int dst0, int src1, int dst1, int ntask) {
        for (int task = wid; task < ntask; task += 16) {
            int tt = task, src = src0, dst = dst0;
            if (tt >= 52) { tt -= 52; src = src1; dst = dst1; }
            const int rt = tt >> 2, ct = tt & 3;
            const int h = ct * 16 + lr;
            const int sw = (h & 7) << 4;
            f32x4 a0 = {0,0,0,0}, a1 = {0,0,0,0};
#pragma unroll
            for (int ks = 0; ks < 7; ++ks) {
                bf8 Bv  = *(const bf8*)(lds + src + ((h * 448 + ks * 64 + lq * 16) ^ sw));
                bf8 S0v = *(const bf8*)(sfr + (size_t)(rt * 7 + ks) * 512 + lane * 8);
                bf8 S1v = *(const bf8*)(sfr + (size_t)((13 + rt) * 7 + ks) * 512 + lane * 8);
                a0 = MFMA(S0v, Bv, a0);
                a1 = MFMA(S1v, Bv, a1);
            }
#pragma unroll
            for (int jj = 0; jj < 4; ++jj) {
                int row = rt * 16 + lq * 4 + jj;
                int rs = (row & 7) << 4;
                *(u16*)(lds + dst + ((row * 256 + h * 2) ^ rs))       = f2b(a0[jj]);
                *(u16*)(lds + dst + ((row * 256 + 128 + h * 2) ^ rs)) = f2b(a1[jj]);
            }
        }
    };

    // ------------------------------------------------------------- the scan
    for (int t = 0; t < T_; ++t) {
        const float* xpk = xpack + (size_t)(b * 24 + t) * N_ * 8;

        // ===== 1. diffuse h0 =====
        diffuseTasks(XT0, XCA, XT0, XCA, 52);
        __syncthreads();

        // ===== 2. dense L0 gates: U pass -> ua, fence, R pass =====
        {
            // ---- U pass
            f32x4 aU[4] = {{0,0,0,0},{0,0,0,0},{0,0,0,0},{0,0,0,0}};
#pragma unroll
            for (int ks = 0; ks < 6; ++ks) {
                bf8 Wu = ldW(wg0b, 128, ks, 64 + o);
#pragma unroll
                for (int i = 0; i < 4; ++i) {
                    int g = rg + 4 * i; if (g > 12) g = 12;
                    bf8 Av = (ks < 2) ? ldX0T(XT0, g, ks)
                           : (ks < 4) ? ldXC(XCA, g, (ks - 2) * 32 + lq * 8)
                                      : ldXC(XCA, g, 64 + (ks - 4) * 32 + lq * 8);
                    aU[i] = MFMA(Av, Wu, aU[i]);
                }
            }
            {
                const float bU = bg0[64 + o];
                float wxu[6];
#pragma unroll
                for (int p = 0; p < 6; ++p) wxu[p] = wxg0[p * 128 + 64 + o];
#pragma unroll
                for (int i = 0; i < 4; ++i) {
                    int g = rg + 4 * i; if (g > 12) g = 12;
#pragma unroll
                    for (int jj = 0; jj < 4; ++jj) {
                        int n = g * 16 + lq * 4 + jj;
                        float vU = aU[i][jj] + bU;
                        if (n < 207) {
                            f32x4 xa = *(const f32x4*)(xpk + n * 8);
                            f32x4 xb = *(const f32x4*)(xpk + n * 8 + 4);
                            vU += xa[0]*wxu[0] + xa[1]*wxu[1] + xa[2]*wxu[2] + xa[3]*wxu[3]
                                + xb[0]*wxu[4] + xb[1]*wxu[5];
                        }
                        ua[i][jj] = sigm(vU);
                    }
                }
            }
            asm volatile("" ::: "memory");   // anti-CSE: keep A-frag reloads in R pass
            // ---- R pass
            f32x4 aR[4] = {{0,0,0,0},{0,0,0,0},{0,0,0,0},{0,0,0,0}};
#pragma unroll
            for (int ks = 0; ks < 6; ++ks) {
                bf8 Wr = ldW(wg0b, 128, ks, o);
#pragma unroll
                for (int i = 0; i < 4; ++i) {
                    int g = rg + 4 * i; if (g > 12) g = 12;
                    bf8 Av = (ks < 2) ? ldX0T(XT0, g, ks)
                           : (ks < 4) ? ldXC(XCA, g, (ks - 2) * 32 + lq * 8)
                                      : ldXC(XCA, g, 64 + (ks - 4) * 32 + lq * 8);
                    aR[i] = MFMA(Av, Wr, aR[i]);
                }
            }
            const float bR = bg0[o];
            float wxr[6];
#pragma unroll
            for (int p = 0; p < 6; ++p) wxr[p] = wxg0[p * 128 + o];
#pragma unroll
            for (int i = 0; i < 4; ++i) {
                int g = rg + 4 * i; if (g > 12) g = 12;
                u16x4 hv;
#pragma unroll
                for (int jj = 0; jj < 4; ++jj) {
                    int n = g * 16 + lq * 4 + jj;
                    float vR = aR[i][jj] + bR;
                    if (n < 207) {
                        f32x4 xa = *(const f32x4*)(xpk + n * 8);
                        f32x4 xb = *(const f32x4*)(xpk + n * 8 + 4);
                        vR += xa[0]*wxr[0] + xa[1]*wxr[1] + xa[2]*wxr[2] + xa[3]*wxr[3]
                            + xb[0]*wxr[4] + xb[1]*wxr[5];
                    }
                    float r = sigm(vR);
                    hv[jj] = f2b(r * h0m[i][jj]);      // rh0
                }
                xtW(XTR, g, hv);
            }
        }
        __syncthreads();

        // ===== 3. diffuse rh0 =====
        diffuseTasks(XTR, XCB, XTR, XCB, 52);
        __syncthreads();

        // ===== 4. dense L0 cand =====
        {
            f32x4 aC[4] = {{0,0,0,0},{0,0,0,0},{0,0,0,0},{0,0,0,0}};
#pragma unroll
            for (int ks = 0; ks < 6; ++ks) {
                bf8 Wv = ldW(wc0b, 64, ks, o);
#pragma unroll
                for (int i = 0; i < 4; ++i) {
                    int g = rg + 4 * i; if (g > 12) g = 12;
                    bf8 Av = (ks < 2) ? ldX0T(XTR, g, ks)
                           : (ks < 4) ? ldXC(XCB, g, (ks - 2) * 32 + lq * 8)
                                      : ldXC(XCB, g, 64 + (ks - 4) * 32 + lq * 8);
                    aC[i] = MFMA(Av, Wv, aC[i]);
                }
            }
            __syncthreads();    // all XTR/XCB reads done before epilogue writes
            const float bC = bc0[o];
            float wxc[6];
#pragma unroll
            for (int p = 0; p < 6; ++p) wxc[p] = wxc0[p * 64 + o];
#pragma unroll
            for (int i = 0; i < 4; ++i) {
                int g = rg + 4 * i; if (g > 12) g = 12;
                u16x4 hv0, hv1;
#pragma unroll
                for (int jj = 0; jj < 4; ++jj) {
                    int n = g * 16 + lq * 4 + jj;
                    float v = aC[i][jj] + bC;
                    if (n < 207) {
                        f32x4 xa = *(const f32x4*)(xpk + n * 8);
                        f32x4 xb = *(const f32x4*)(xpk + n * 8 + 4);
                        v += xa[0]*wxc[0] + xa[1]*wxc[1] + xa[2]*wxc[2] + xa[3]*wxc[3]
                           + xb[0]*wxc[4] + xb[1]*wxc[5];
                    }
                    float cv = tanh_f(v);
                    float hn = ua[i][jj] * h0m[i][jj] + (1.f - ua[i][jj]) * cv;
                    h0m[i][jj] = hn;
                    hv0[jj] = f2b(hn);                 // h0new
                    hv1[jj] = f2b(h1m[i][jj]);         // h1 (for L1 diffusion)
                }
                xtW(XT0, g, hv0);
                xtW(XTR, g, hv1);
            }
        }
        __syncthreads();

        // ===== 5. dual diffuse: h0new -> XCA, h1 -> XCB =====
        diffuseTasks(XT0, XCA, XTR, XCB, 104);
        __syncthreads();

        // ===== 6. dense L1 gates: U pass -> ua, fence, R pass =====
        {
            // ---- U pass
            f32x4 aU[4] = {{0,0,0,0},{0,0,0,0},{0,0,0,0},{0,0,0,0}};
#pragma unroll
            for (int ks = 0; ks < 12; ++ks) {
                bf8 Wu = ldW(wg1b, 128, ks, 64 + o);
#pragma unroll
                for (int i = 0; i < 4; ++i) {
                    int g = rg + 4 * i; if (g > 12) g = 12;
                    bf8 Av;
                    if (ks < 2)       Av = ldX0T(XT0, g, ks);
                    else if (ks < 4)  Av = ldX0T(XTR, g, ks - 2);
                    else if (ks < 6)  Av = ldXC(XCA, g, (ks - 4) * 32 + lq * 8);
                    else if (ks < 8)  Av = ldXC(XCB, g, (ks - 6) * 32 + lq * 8);
                    else if (ks < 10) Av = ldXC(XCA, g, 64 + (ks - 8) * 32 + lq * 8);
                    else              Av = ldXC(XCB, g, 64 + (ks - 10) * 32 + lq * 8);
                    aU[i] = MFMA(Av, Wu, aU[i]);
                }
            }
            {
                const float bU = bg1[64 + o];
#pragma unroll
                for (int i = 0; i < 4; ++i)
#pragma unroll
                    for (int jj = 0; jj < 4; ++jj)
                        ua[i][jj] = sigm(aU[i][jj] + bU);
            }
            asm volatile("" ::: "memory");   // anti-CSE
            // ---- R pass
            f32x4 aR[4] = {{0,0,0,0},{0,0,0,0},{0,0,0,0},{0,0,0,0}};
#pragma unroll
            for (int ks = 0; ks < 12; ++ks) {
                bf8 Wr = ldW(wg1b, 128, ks, o);
#pragma unroll
                for (int i = 0; i < 4; ++i) {
                    int g = rg + 4 * i; if (g > 12) g = 12;
                    bf8 Av;
                    if (ks < 2)       Av = ldX0T(XT0, g, ks);
                    else if (ks < 4)  Av = ldX0T(XTR, g, ks - 2);
                    else if (ks < 6)  Av = ldXC(XCA, g, (ks - 4) * 32 + lq * 8);
                    else if (ks < 8)  Av = ldXC(XCB, g, (ks - 6) * 32 + lq * 8);
                    else if (ks < 10) Av = ldXC(XCA, g, 64 + (ks - 8) * 32 + lq * 8);
                    else              Av = ldXC(XCB, g, 64 + (ks - 10) * 32 + lq * 8);
                    aR[i] = MFMA(Av, Wr, aR[i]);
                }
            }
            __syncthreads();    // all XTR reads done before rh1 writes
            const float bR = bg1[o];
#pragma unroll
            for (int i = 0; i < 4; ++i) {
                int g = rg + 4 * i; if (g > 12) g = 12;
                u16x4 hv;
#pragma unroll
                for (int jj = 0; jj < 4; ++jj) {
                    float r1 = sigm(aR[i][jj] + bR);
                    hv[jj] = f2b(r1 * h1m[i][jj]);     // rh1
                }
                xtW(XTR, g, hv);
            }
        }
        __syncthreads();

        // ===== 7. diffuse rh1 -> XCB =====
        diffuseTasks(XTR, XCB, XTR, XCB, 52);
        __syncthreads();

        // ===== 8. dense L1 cand + GRU + out_cur =====
        {
            f32x4 aC[4] = {{0,0,0,0},{0,0,0,0},{0,0,0,0},{0,0,0,0}};
#pragma unroll
            for (int ks = 0; ks < 12; ++ks) {
                bf8 Wv = ldW(wc1b, 64, ks, o);
#pragma unroll
                for (int i = 0; i < 4; ++i) {
                    int g = rg + 4 * i; if (g > 12) g = 12;
                    bf8 Av;
                    if (ks < 2)       Av = ldX0T(XT0, g, ks);
                    else if (ks < 4)  Av = ldX0T(XTR, g, ks - 2);
                    else if (ks < 6)  Av = ldXC(XCA, g, (ks - 4) * 32 + lq * 8);
                    else if (ks < 8)  Av = ldXC(XCB, g, (ks - 6) * 32 + lq * 8);
                    else if (ks < 10) Av = ldXC(XCA, g, 64 + (ks - 8) * 32 + lq * 8);
                    else              Av = ldXC(XCB, g, 64 + (ks - 10) * 32 + lq * 8);
                    aC[i] = MFMA(Av, Wv, aC[i]);
                }
            }
            const float bC = bc1[o];
            float* oc = out_cur + (size_t)(t * B_ + b) * 13248;
#pragma unroll
            for (int i = 0; i < 4; ++i) {
                int g = rg + 4 * i; if (g > 12) g = 12;
#pragma unroll
                for (int jj = 0; jj < 4; ++jj) {
                    int n = g * 16 + lq * 4 + jj;
                    float cv = tanh_f(aC[i][jj] + bC);
                    float hn = ua[i][jj] * h1m[i][jj] + (1.f - ua[i][jj]) * cv;
                    h1m[i][jj] = hn;
                    if (n < 207) oc[n * 64 + o] = hn;
                }
            }
        }
        __syncthreads();
    }

    // ---- final hidden state (duplicate stores are bit-identical -> benign)
#pragma unroll
    for (int i = 0; i < 4; ++i) {
        int g = rg + 4 * i; if (g > 12) g = 12;
#pragma unroll
        for (int jj = 0; jj < 4; ++jj) {
            int n = g * 16 + lq * 4 + jj;
            if (n < 207) {
                out_hid[(size_t)b * 13248 + n * 64 + o] = h0m[i][jj];
                out_hid[(size_t)BNH + (size_t)b * 13248 + n * 64 + o] = h1m[i][jj];
            }
        }
    }
}

// ---------------------------------------------------------------------- launch
extern "C" void kernel_launch(void* const* d_in, const int* in_sizes, int n_in,
                              void* d_out, int out_size, void* d_ws, size_t ws_size,
                              hipStream_t stream) {
    const float* x   = (const float*)d_in[0];
    const float* ih  = (const float*)d_in[1];
    const float* S   = (const float*)d_in[2];
    const float* wg0 = (const float*)d_in[3];
    const float* bg0 = (const float*)d_in[4];
    const float* wc0 = (const float*)d_in[5];
    const float* bc0 = (const float*)d_in[6];
    const float* wg1 = (const float*)d_in[7];
    const float* bg1 = (const float*)d_in[8];
    const float* wc1 = (const float*)d_in[9];
    const float* bc1 = (const float*)d_in[10];

    char* p = (char*)d_ws;
    auto alloc = [&](size_t bytes) -> char* {
        char* r = p; p += (bytes + 255) & ~(size_t)255; return r;
    };
    float* S2    = (float*)alloc((size_t)N_ * N_ * 4);
    u16*   sfr   = (u16*)  alloc(93184 * 2);
    u16*   wg0b  = (u16*)  alloc(24576 * 2);
    u16*   wc0b  = (u16*)  alloc(12288 * 2);
    u16*   wg1b  = (u16*)  alloc(49152 * 2);
    u16*   wc1b  = (u16*)  alloc(24576 * 2);
    float* wxg0  = (float*)alloc(6 * 128 * 4);
    float* wxc0  = (float*)alloc(6 * 64 * 4);
    u16*   xt2   = (u16*)  alloc((size_t)N_ * 3072 * 2);
    float* xpack = (float*)alloc((size_t)B_ * 24 * N_ * 8 * 4);

    float* out     = (float*)d_out;
    float* out_cur = out + 2 * (size_t)BNH;

    // ---- prep (small, parallel)
    s2_kernel  <<<N_, 256, 0, stream>>>(S, S2);
    sfr_build  <<<364, 256, 0, stream>>>(S, S2, sfr);
    wblk_build <<<96,  256, 0, stream>>>(wg0, wg0b, 128, 24576, 0);
    wblk_build <<<48,  256, 0, stream>>>(wc0, wc0b,  64, 12288, 0);
    wblk_build <<<192, 256, 0, stream>>>(wg1, wg1b, 128, 49152, 1);
    wblk_build <<<96,  256, 0, stream>>>(wc1, wc1b,  64, 24576, 1);
    wx_build   <<<3, 256, 0, stream>>>(wg0, wxg0, 128);
    wx_build   <<<2, 256, 0, stream>>>(wc0, wxc0, 64);
    xt2_build  <<<2484, 256, 0, stream>>>(x, xt2);
    xpack_build<<<dim3(N_, 6), 256, 0, stream>>>(S, S2, xt2, xpack);

    // ---- the whole scan: 64 independent blocks
    dcrnn_scan<<<64, 1024, LDS_TOTAL, stream>>>(
        sfr, wg0b, bg0, wxg0, wc0b, bc0, wxc0, wg1b, bg1, wc1b, bc1,
        xpack, ih, out, out_cur);
}

// Round 10
// 3660.151 us; speedup vs baseline: 1.1413x; 1.1413x over previous
//
#include <hip/hip_runtime.h>
#include <math.h>

// DCRNN encoder: one block per batch element (64 blocks x 1024 thr = 16 waves).
// Round-10: round-8 structure (fused dual-accumulator gates) + the spill fix:
//  - STATIC 160 KiB LDS (backend now sees occupancy = 1 WG/CU -> VGPR target 128,
//    not the dynamic-LDS-blind 64 that caused 2-3 GB of scratch traffic)
//  - __launch_bounds__(1024, 4): min 4 waves/EU -> VGPR cap 128 (HIP-documented)
// 8-phase schedule, two diffusion buffers XCA/XCB, no accumulator lives across
// a diffusion; x0 dense fragments via scalar reads from transposed buffers.
// S2=2*S@S precomputed; x2=S2@x0-x0 with -x0 folded into W (W0' = W0-W2).
// Layer-0 x-part precomputed for all T (xpack), added in epilogue.

typedef unsigned short u16;
typedef unsigned int u32;
typedef short bf8 __attribute__((ext_vector_type(8)));
typedef u16 u16x4 __attribute__((ext_vector_type(4)));
typedef u16 u16x8 __attribute__((ext_vector_type(8)));
typedef float f32x4 __attribute__((ext_vector_type(4)));

constexpr int T_ = 24, B_ = 64, N_ = 207, H_ = 64;
constexpr int BNH = B_ * N_ * H_;      // 847872

// LDS map (total exactly 163840 B = 160 KiB)
constexpr int XT0 = 0;                 // 28672: [64 h][224 m] bf16 h0^T, pitch 448, ^((h&7)<<4)
constexpr int XTR = 28672;             // 28672: transposed scratch (rh0 / h1 / rh1)
constexpr int XCA = 57344;             // 53248: [208 n][128 k] bf16 diff out A, pitch 256, ^((n&7)<<4)
constexpr int XCB = 110592;            // 53248: diff out B
constexpr int LDS_TOTAL = 163840;

#define MFMA(a, bb, c) __builtin_amdgcn_mfma_f32_16x16x32_bf16(a, bb, c, 0, 0, 0)

__device__ __forceinline__ float b2f(u16 b) {
    u32 u = ((u32)b) << 16; float f; __builtin_memcpy(&f, &u, 4); return f;
}
__device__ __forceinline__ u16 f2b(float f) {
    u32 u; __builtin_memcpy(&u, &f, 4);
    return (u16)((u + 0x7FFF + ((u >> 16) & 1)) >> 16);
}
__device__ __forceinline__ float sigm(float v) { return 1.f / (1.f + __expf(-v)); }
__device__ __forceinline__ float tanh_f(float v) {
    return 1.f - 2.f / (__expf(2.f * v) + 1.f);
}

// ---------------------------------------------------------------- S2 = 2*S@S
__global__ void s2_kernel(const float* __restrict__ S, float* __restrict__ S2) {
    const int n = blockIdx.x, m = threadIdx.x;
    if (m >= N_) return;
    float acc = 0.f;
    for (int k = 0; k < N_; ++k) acc += S[n * N_ + k] * S[k * N_ + m];
    S2[n * N_ + m] = 2.f * acc;
}

// ---------------------- S fragments: sfr[half 2][rt 13][ks 7][lane 64][j 8]
__global__ void sfr_build(const float* __restrict__ S, const float* __restrict__ S2,
                          u16* __restrict__ sfr) {
    int idx = blockIdx.x * 256 + threadIdx.x;
    if (idx >= 2 * 13 * 7 * 64 * 8) return;   // 93184
    int jj = idx & 7;
    int lane = (idx >> 3) & 63;
    int rest = idx >> 9;
    int ks = rest % 7; rest /= 7;
    int rt = rest % 13, half = rest / 13;
    int node = rt * 16 + (lane & 15);
    int k = ks * 32 + (lane >> 4) * 8 + jj;
    float v = 0.f;
    if (node < N_ && k < N_) v = half ? S2[node * N_ + k] : S[node * N_ + k];
    sfr[idx] = f2b(v);
}

// ------------------------------------------------ W blocked to fragment order
__global__ void wblk_build(const float* __restrict__ W, u16* __restrict__ out,
                           int OF, int total, int layer) {
    int idx = blockIdx.x * 256 + threadIdx.x;
    if (idx >= total) return;
    int j = idx & 7;
    int rest = idx >> 3;
    int o = rest % OF; rest /= OF;
    int kb = rest & 3, ks = rest >> 2;
    int k = ks * 32 + kb * 8 + j;
    int blk = k >> 6, d = k & 63;
    int wrow, wsub = -1;
    if (layer == 0) {                       // [x0h, x1h, x2h], D=66
        wrow = blk * 66 + 2 + d;
        if (blk == 0) wsub = 2 * 66 + 2 + d;
    } else {                                // [x0x,x0h,x1x,x1h,x2x,x2h], D=128
        int sb = blk >> 1, part = blk & 1;
        wrow = sb * 128 + part * 64 + d;
        if (sb == 0) wsub = 256 + part * 64 + d;
    }
    float v = W[wrow * OF + o];
    if (wsub >= 0) v -= W[wsub * OF + o];
    out[idx] = f2b(v);
}

// ------------------------------------- layer-0 x-feature weight slice (f32)
__global__ void wx_build(const float* __restrict__ W, float* __restrict__ out, int OF) {
    int idx = blockIdx.x * 256 + threadIdx.x;
    if (idx >= 6 * OF) return;
    int o = idx % OF, p = idx / OF;
    int cheb = p >> 1, i = p & 1;
    float v = W[(cheb * 66 + i) * OF + o];
    if (cheb == 0) v -= W[(132 + i) * OF + o];
    out[idx] = v;
}

// ------------------------------------- x transpose: [T,B,N,2] -> [n][t][b][i]
__global__ void xt2_build(const float* __restrict__ x, u16* __restrict__ xt2) {
    int idx = blockIdx.x * 256 + threadIdx.x;
    if (idx >= N_ * T_ * B_ * 2) return;
    int i = idx & 1, b = (idx >> 1) & 63, rest = idx >> 7;
    int t = rest % T_, n = rest / T_;
    xt2[idx] = f2b(x[((t * B_ + b) * N_ + n) * 2 + i]);
}

// ----------------- layer-0 x part, all T: xpack[b][t][n][8] = [x0,x1,S@x,S2@x]
__global__ __launch_bounds__(256) void xpack_build(const float* __restrict__ S,
                                                   const float* __restrict__ S2,
                                                   const u16* __restrict__ xt2,
                                                   float* __restrict__ xpack) {
    __shared__ float sS[N_], sS2[N_];
    int n = blockIdx.x;
    for (int i = threadIdx.x; i < N_; i += 256) { sS[i] = S[n*N_+i]; sS2[i] = S2[n*N_+i]; }
    __syncthreads();
    int c = blockIdx.y * 256 + threadIdx.x;   // < 1536 = T*B
    float a10 = 0, a11 = 0, a20 = 0, a21 = 0;
    for (int m = 0; m < N_; ++m) {
        float x0 = b2f(xt2[m * 3072 + c * 2]);
        float x1 = b2f(xt2[m * 3072 + c * 2 + 1]);
        a10 += sS[m] * x0;  a11 += sS[m] * x1;
        a20 += sS2[m] * x0; a21 += sS2[m] * x1;
    }
    int t = c >> 6, bb = c & 63;
    float* p = xpack + (size_t)((bb * 24 + t) * N_ + n) * 8;
    p[0] = b2f(xt2[n * 3072 + c * 2]); p[1] = b2f(xt2[n * 3072 + c * 2 + 1]);
    p[2] = a10; p[3] = a11; p[4] = a20; p[5] = a21; p[6] = 0.f; p[7] = 0.f;
}

// --------------------------------------------------------------- scan kernel
__global__ __launch_bounds__(1024, 4)
void dcrnn_scan(
    const u16* __restrict__ sfr,
    const u16* __restrict__ wg0b, const float* __restrict__ bg0, const float* __restrict__ wxg0,
    const u16* __restrict__ wc0b, const float* __restrict__ bc0, const float* __restrict__ wxc0,
    const u16* __restrict__ wg1b, const float* __restrict__ bg1,
    const u16* __restrict__ wc1b, const float* __restrict__ bc1,
    const float* __restrict__ xpack, const float* __restrict__ ih,
    float* __restrict__ out_hid, float* __restrict__ out_cur)
{
    __shared__ __align__(16) char lds[LDS_TOTAL];   // STATIC: backend sees 1 WG/CU
    const int tid  = threadIdx.x;
    const int lane = tid & 63, wid = tid >> 6;        // 16 waves
    const int lq = lane >> 4, lr = lane & 15;
    const int j = wid >> 2, rg = wid & 3;             // o-tile j, node-split rg
    const int o = j * 16 + lr;
    const int b = blockIdx.x;

    // ---- zero all LDS (pads must be finite-zero)
    {
        u16x8 z = {0,0,0,0,0,0,0,0};
        for (int i = tid; i < LDS_TOTAL / 16; i += 1024)
            *(u16x8*)(lds + i * 16) = z;
    }
    __syncthreads();

    // ---- init: XT0 <- h0^T ; masters from ih (clamped-group duplicates)
    const float* ih0 = ih + (size_t)b * 13248;
    const float* ih1 = ih + (size_t)BNH + (size_t)b * 13248;
    for (int idx = tid; idx < 13248; idx += 1024) {
        int n = idx >> 6, oo = idx & 63;
        *(u16*)(lds + XT0 + ((oo * 448 + n * 2) ^ ((oo & 7) << 4))) = f2b(ih0[idx]);
    }
    float h0m[4][4], h1m[4][4], ua[4][4];
#pragma unroll
    for (int i = 0; i < 4; ++i) {
        int g = rg + 4 * i; if (g > 12) g = 12;
#pragma unroll
        for (int jj = 0; jj < 4; ++jj) {
            int n = g * 16 + lq * 4 + jj;
            h0m[i][jj] = (n < 207) ? ih0[n * 64 + o] : 0.f;
            h1m[i][jj] = (n < 207) ? ih1[n * 64 + o] : 0.f;
            ua[i][jj] = 0.f;
        }
    }
    __syncthreads();

    // ---- helpers
    auto ldXC = [&](int base, int g, int koff) -> bf8 {
        int row = g * 16 + lr;
        return *(const bf8*)(lds + base + ((row * 256 + koff * 2) ^ ((row & 7) << 4)));
    };
    // x0 A-fragment from a transposed buffer: 8 scalar reads (f = ks*32+8lq+j)
    auto ldX0T = [&](int xtOff, int g, int ks) -> bf8 {
        bf8 r;
        const int n2 = (g * 16 + lr) * 2;
        const int fb = ks * 32 + lq * 8;
#pragma unroll
        for (int e = 0; e < 8; ++e)
            r[e] = *(const short*)(lds + xtOff + (((fb + e) * 448 + n2) ^ ((e & 7) << 4)));
        return r;
    };
    auto xtW = [&](int dst, int g, u16x4 hv) {
        int nb = g * 16 + lq * 4;
        *(u16x4*)(lds + dst + ((o * 448 + nb * 2) ^ ((o & 7) << 4))) = hv;
    };
    auto ldW = [&](const u16* w, int OF, int ks, int oo) -> bf8 {
        return *(const bf8*)(w + (size_t)((ks * 4 + lq) * OF + oo) * 8);
    };
    // diffusion tasks: (rt,ct) grid; dual-phase runs 104 tasks (two src/dst pairs)
    auto diffuseTasks = [&](int src0, int dst0, int src1, int dst1, int ntask) {
        for (int task = wid; task < ntask; task += 16) {
            int tt = task, src = src0, dst = dst0;
            if (tt >= 52) { tt -= 52; src = src1; dst = dst1; }
            const int rt = tt >> 2, ct = tt & 3;
            const int h = ct * 16 + lr;
            const int sw = (h & 7) << 4;
            f32x4 a0 = {0,0,0,0}, a1 = {0,0,0,0};
#pragma unroll
            for (int ks = 0; ks < 7; ++ks) {
                bf8 Bv  = *(const bf8*)(lds + src + ((h * 448 + ks * 64 + lq * 16) ^ sw));
                bf8 S0v = *(const bf8*)(sfr + (size_t)(rt * 7 + ks) * 512 + lane * 8);
                bf8 S1v = *(const bf8*)(sfr + (size_t)((13 + rt) * 7 + ks) * 512 + lane * 8);
                a0 = MFMA(S0v, Bv, a0);
                a1 = MFMA(S1v, Bv, a1);
            }
#pragma unroll
            for (int jj = 0; jj < 4; ++jj) {
                int row = rt * 16 + lq * 4 + jj;
                int rs = (row & 7) << 4;
                *(u16*)(lds + dst + ((row * 256 + h * 2) ^ rs))       = f2b(a0[jj]);
                *(u16*)(lds + dst + ((row * 256 + 128 + h * 2) ^ rs)) = f2b(a1[jj]);
            }
        }
    };

    // ------------------------------------------------------------- the scan
    for (int t = 0; t < T_; ++t) {
        const float* xpk = xpack + (size_t)(b * 24 + t) * N_ * 8;

        // ===== 1. diffuse h0 =====
        diffuseTasks(XT0, XCA, XT0, XCA, 52);
        __syncthreads();

        // ===== 2. dense L0 gates =====
        {
            f32x4 aR[4] = {{0,0,0,0},{0,0,0,0},{0,0,0,0},{0,0,0,0}};
            f32x4 aU[4] = {{0,0,0,0},{0,0,0,0},{0,0,0,0},{0,0,0,0}};
#pragma unroll
            for (int ks = 0; ks < 6; ++ks) {
                bf8 Wr = ldW(wg0b, 128, ks, o);
                bf8 Wu = ldW(wg0b, 128, ks, 64 + o);
#pragma unroll
                for (int i = 0; i < 4; ++i) {
                    int g = rg + 4 * i; if (g > 12) g = 12;
                    bf8 Av = (ks < 2) ? ldX0T(XT0, g, ks)
                           : (ks < 4) ? ldXC(XCA, g, (ks - 2) * 32 + lq * 8)
                                      : ldXC(XCA, g, 64 + (ks - 4) * 32 + lq * 8);
                    aR[i] = MFMA(Av, Wr, aR[i]);
                    aU[i] = MFMA(Av, Wu, aU[i]);
                }
            }
            const float bR = bg0[o], bU = bg0[64 + o];
            float wxr[6], wxu[6];
#pragma unroll
            for (int p = 0; p < 6; ++p) { wxr[p] = wxg0[p * 128 + o]; wxu[p] = wxg0[p * 128 + 64 + o]; }
#pragma unroll
            for (int i = 0; i < 4; ++i) {
                int g = rg + 4 * i; if (g > 12) g = 12;
                u16x4 hv;
#pragma unroll
                for (int jj = 0; jj < 4; ++jj) {
                    int n = g * 16 + lq * 4 + jj;
                    float vR = aR[i][jj] + bR, vU = aU[i][jj] + bU;
                    if (n < 207) {
                        f32x4 xa = *(const f32x4*)(xpk + n * 8);
                        f32x4 xb = *(const f32x4*)(xpk + n * 8 + 4);
                        vR += xa[0]*wxr[0] + xa[1]*wxr[1] + xa[2]*wxr[2] + xa[3]*wxr[3]
                            + xb[0]*wxr[4] + xb[1]*wxr[5];
                        vU += xa[0]*wxu[0] + xa[1]*wxu[1] + xa[2]*wxu[2] + xa[3]*wxu[3]
                            + xb[0]*wxu[4] + xb[1]*wxu[5];
                    }
                    float r = sigm(vR);
                    ua[i][jj] = sigm(vU);
                    hv[jj] = f2b(r * h0m[i][jj]);      // rh0
                }
                xtW(XTR, g, hv);
            }
        }
        __syncthreads();

        // ===== 3. diffuse rh0 =====
        diffuseTasks(XTR, XCB, XTR, XCB, 52);
        __syncthreads();

        // ===== 4. dense L0 cand =====
        {
            f32x4 aC[4] = {{0,0,0,0},{0,0,0,0},{0,0,0,0},{0,0,0,0}};
#pragma unroll
            for (int ks = 0; ks < 6; ++ks) {
                bf8 Wv = ldW(wc0b, 64, ks, o);
#pragma unroll
                for (int i = 0; i < 4; ++i) {
                    int g = rg + 4 * i; if (g > 12) g = 12;
                    bf8 Av = (ks < 2) ? ldX0T(XTR, g, ks)
                           : (ks < 4) ? ldXC(XCB, g, (ks - 2) * 32 + lq * 8)
                                      : ldXC(XCB, g, 64 + (ks - 4) * 32 + lq * 8);
                    aC[i] = MFMA(Av, Wv, aC[i]);
                }
            }
            __syncthreads();    // all XTR/XCB reads done before epilogue writes
            const float bC = bc0[o];
            float wxc[6];
#pragma unroll
            for (int p = 0; p < 6; ++p) wxc[p] = wxc0[p * 64 + o];
#pragma unroll
            for (int i = 0; i < 4; ++i) {
                int g = rg + 4 * i; if (g > 12) g = 12;
                u16x4 hv0, hv1;
#pragma unroll
                for (int jj = 0; jj < 4; ++jj) {
                    int n = g * 16 + lq * 4 + jj;
                    float v = aC[i][jj] + bC;
                    if (n < 207) {
                        f32x4 xa = *(const f32x4*)(xpk + n * 8);
                        f32x4 xb = *(const f32x4*)(xpk + n * 8 + 4);
                        v += xa[0]*wxc[0] + xa[1]*wxc[1] + xa[2]*wxc[2] + xa[3]*wxc[3]
                           + xb[0]*wxc[4] + xb[1]*wxc[5];
                    }
                    float cv = tanh_f(v);
                    float hn = ua[i][jj] * h0m[i][jj] + (1.f - ua[i][jj]) * cv;
                    h0m[i][jj] = hn;
                    hv0[jj] = f2b(hn);                 // h0new
                    hv1[jj] = f2b(h1m[i][jj]);         // h1 (for L1 diffusion)
                }
                xtW(XT0, g, hv0);
                xtW(XTR, g, hv1);
            }
        }
        __syncthreads();

        // ===== 5. dual diffuse: h0new -> XCA, h1 -> XCB =====
        diffuseTasks(XT0, XCA, XTR, XCB, 104);
        __syncthreads();

        // ===== 6. dense L1 gates =====
        {
            f32x4 aR[4] = {{0,0,0,0},{0,0,0,0},{0,0,0,0},{0,0,0,0}};
            f32x4 aU[4] = {{0,0,0,0},{0,0,0,0},{0,0,0,0},{0,0,0,0}};
#pragma unroll
            for (int ks = 0; ks < 12; ++ks) {
                bf8 Wr = ldW(wg1b, 128, ks, o);
                bf8 Wu = ldW(wg1b, 128, ks, 64 + o);
#pragma unroll
                for (int i = 0; i < 4; ++i) {
                    int g = rg + 4 * i; if (g > 12) g = 12;
                    bf8 Av;
                    if (ks < 2)       Av = ldX0T(XT0, g, ks);
                    else if (ks < 4)  Av = ldX0T(XTR, g, ks - 2);
                    else if (ks < 6)  Av = ldXC(XCA, g, (ks - 4) * 32 + lq * 8);
                    else if (ks < 8)  Av = ldXC(XCB, g, (ks - 6) * 32 + lq * 8);
                    else if (ks < 10) Av = ldXC(XCA, g, 64 + (ks - 8) * 32 + lq * 8);
                    else              Av = ldXC(XCB, g, 64 + (ks - 10) * 32 + lq * 8);
                    aR[i] = MFMA(Av, Wr, aR[i]);
                    aU[i] = MFMA(Av, Wu, aU[i]);
                }
            }
            __syncthreads();    // all XTR reads done before rh1 writes
            const float bR = bg1[o], bU = bg1[64 + o];
#pragma unroll
            for (int i = 0; i < 4; ++i) {
                int g = rg + 4 * i; if (g > 12) g = 12;
                u16x4 hv;
#pragma unroll
                for (int jj = 0; jj < 4; ++jj) {
                    float r1 = sigm(aR[i][jj] + bR);
                    ua[i][jj] = sigm(aU[i][jj] + bU);
                    hv[jj] = f2b(r1 * h1m[i][jj]);     // rh1
                }
                xtW(XTR, g, hv);
            }
        }
        __syncthreads();

        // ===== 7. diffuse rh1 -> XCB =====
        diffuseTasks(XTR, XCB, XTR, XCB, 52);
        __syncthreads();

        // ===== 8. dense L1 cand + GRU + out_cur =====
        {
            f32x4 aC[4] = {{0,0,0,0},{0,0,0,0},{0,0,0,0},{0,0,0,0}};
#pragma unroll
            for (int ks = 0; ks < 12; ++ks) {
                bf8 Wv = ldW(wc1b, 64, ks, o);
#pragma unroll
                for (int i = 0; i < 4; ++i) {
                    int g = rg + 4 * i; if (g > 12) g = 12;
                    bf8 Av;
                    if (ks < 2)       Av = ldX0T(XT0, g, ks);
                    else if (ks < 4)  Av = ldX0T(XTR, g, ks - 2);
                    else if (ks < 6)  Av = ldXC(XCA, g, (ks - 4) * 32 + lq * 8);
                    else if (ks < 8)  Av = ldXC(XCB, g, (ks - 6) * 32 + lq * 8);
                    else if (ks < 10) Av = ldXC(XCA, g, 64 + (ks - 8) * 32 + lq * 8);
                    else              Av = ldXC(XCB, g, 64 + (ks - 10) * 32 + lq * 8);
                    aC[i] = MFMA(Av, Wv, aC[i]);
                }
            }
            const float bC = bc1[o];
            float* oc = out_cur + (size_t)(t * B_ + b) * 13248;
#pragma unroll
            for (int i = 0; i < 4; ++i) {
                int g = rg + 4 * i; if (g > 12) g = 12;
#pragma unroll
                for (int jj = 0; jj < 4; ++jj) {
                    int n = g * 16 + lq * 4 + jj;
                    float cv = tanh_f(aC[i][jj] + bC);
                    float hn = ua[i][jj] * h1m[i][jj] + (1.f - ua[i][jj]) * cv;
                    h1m[i][jj] = hn;
                    if (n < 207) oc[n * 64 + o] = hn;
                }
            }
        }
        __syncthreads();
    }

    // ---- final hidden state (duplicate stores are bit-identical -> benign)
#pragma unroll
    for (int i = 0; i < 4; ++i) {
        int g = rg + 4 * i; if (g > 12) g = 12;
#pragma unroll
        for (int jj = 0; jj < 4; ++jj) {
            int n = g * 16 + lq * 4 + jj;
            if (n < 207) {
                out_hid[(size_t)b * 13248 + n * 64 + o] = h0m[i][jj];
                out_hid[(size_t)BNH + (size_t)b * 13248 + n * 64 + o] = h1m[i][jj];
            }
        }
    }
}

// ---------------------------------------------------------------------- launch
extern "C" void kernel_launch(void* const* d_in, const int* in_sizes, int n_in,
                              void* d_out, int out_size, void* d_ws, size_t ws_size,
                              hipStream_t stream) {
    const float* x   = (const float*)d_in[0];
    const float* ih  = (const float*)d_in[1];
    const float* S   = (const float*)d_in[2];
    const float* wg0 = (const float*)d_in[3];
    const float* bg0 = (const float*)d_in[4];
    const float* wc0 = (const float*)d_in[5];
    const float* bc0 = (const float*)d_in[6];
    const float* wg1 = (const float*)d_in[7];
    const float* bg1 = (const float*)d_in[8];
    const float* wc1 = (const float*)d_in[9];
    const float* bc1 = (const float*)d_in[10];

    char* p = (char*)d_ws;
    auto alloc = [&](size_t bytes) -> char* {
        char* r = p; p += (bytes + 255) & ~(size_t)255; return r;
    };
    float* S2    = (float*)alloc((size_t)N_ * N_ * 4);
    u16*   sfr   = (u16*)  alloc(93184 * 2);
    u16*   wg0b  = (u16*)  alloc(24576 * 2);
    u16*   wc0b  = (u16*)  alloc(12288 * 2);
    u16*   wg1b  = (u16*)  alloc(49152 * 2);
    u16*   wc1b  = (u16*)  alloc(24576 * 2);
    float* wxg0  = (float*)alloc(6 * 128 * 4);
    float* wxc0  = (float*)alloc(6 * 64 * 4);
    u16*   xt2   = (u16*)  alloc((size_t)N_ * 3072 * 2);
    float* xpack = (float*)alloc((size_t)B_ * 24 * N_ * 8 * 4);

    float* out     = (float*)d_out;
    float* out_cur = out + 2 * (size_t)BNH;

    // ---- prep (small, parallel)
    s2_kernel  <<<N_, 256, 0, stream>>>(S, S2);
    sfr_build  <<<364, 256, 0, stream>>>(S, S2, sfr);
    wblk_build <<<96,  256, 0, stream>>>(wg0, wg0b, 128, 24576, 0);
    wblk_build <<<48,  256, 0, stream>>>(wc0, wc0b,  64, 12288, 0);
    wblk_build <<<192, 256, 0, stream>>>(wg1, wg1b, 128, 49152, 1);
    wblk_build <<<96,  256, 0, stream>>>(wc1, wc1b,  64, 24576, 1);
    wx_build   <<<3, 256, 0, stream>>>(wg0, wxg0, 128);
    wx_build   <<<2, 256, 0, stream>>>(wc0, wxc0, 64);
    xt2_build  <<<2484, 256, 0, stream>>>(x, xt2);
    xpack_build<<<dim3(N_, 6), 256, 0, stream>>>(S, S2, xt2, xpack);

    // ---- the whole scan: 64 independent blocks (static 160 KiB LDS)
    dcrnn_scan<<<64, 1024, 0, stream>>>(
        sfr, wg0b, bg0, wxg0, wc0b, bc0, wxc0, wg1b, bg1, wc1b, bc1,
        xpack, ih, out, out_cur);
}